// Round 2
// baseline (338.952 us; speedup 1.0000x reference)
//
#include <hip/hip_runtime.h>

typedef unsigned short u16;
typedef unsigned int u32;
typedef __attribute__((ext_vector_type(4))) float f32x4;
typedef __attribute__((ext_vector_type(8))) short s16x8;
typedef __attribute__((ext_vector_type(4))) short s16x4;

#define DEV static __device__ __forceinline__

DEV u16 f2bf(float f){ union{float f;u32 u;}x; x.f=f; u32 u = x.u + 0x7fffu + ((x.u>>16)&1u); return (u16)(u>>16); }
DEV float bf2f(u16 v){ union{u32 u;float f;}x; x.u = ((u32)v)<<16; return x.f; }

DEV f32x4 MF(s16x8 a, s16x8 b, f32x4 c){ return __builtin_amdgcn_mfma_f32_16x16x32_bf16(a,b,c,0,0,0); }

// read a 16B MFMA fragment from a swizzled [rows][64] bf16 LDS tile
DEV s16x8 frag64(const u16* lds, int row, int slot){
  return *(const s16x8*)(lds + row*64 + ((slot ^ (row&7))<<3));
}
// stage a 64-row x 64-col bf16 tile into swizzled LDS; 256-thread version (2 chunks/thread)
DEV void stage64_256(u16* dst, const u16* src, int srcStride, int t){
#pragma unroll
  for (int i=0;i<2;i++){
    int id = t + 256*i; int row = id>>3, slot = id&7;
    s16x8 v = *(const s16x8*)(src + row*srcStride + slot*8);
    *(s16x8*)(dst + row*64 + ((slot^(row&7))<<3)) = v;
  }
}
// 512-thread version (1 chunk/thread)
DEV void stage64_512(u16* dst, const u16* src, int srcStride, int t){
  int row = t>>3, slot = t&7;
  s16x8 v = *(const s16x8*)(src + row*srcStride + slot*8);
  *(s16x8*)(dst + row*64 + ((slot^(row&7))<<3)) = v;
}

// ---------------- prep: W[k][n] f32 -> WT[n][k] bf16, 5 matrices ----------------
__global__ __launch_bounds__(256) void k_prep(
  const float* __restrict__ Wq, const float* __restrict__ Wk, const float* __restrict__ Wv,
  const float* __restrict__ Wp, const float* __restrict__ Wo, u16* __restrict__ WT)
{
  const int bx = blockIdx.x; const int mat = bx>>6, tile = bx&63;
  const float* W = (mat==0)?Wq:(mat==1)?Wk:(mat==2)?Wv:(mat==3)?Wp:Wo;
  u16* dst = WT + mat*262144;
  const int k0 = (tile>>3)<<6, n0 = (tile&7)<<6;
  __shared__ u16 L[64*68];
  const int t = threadIdx.x;
#pragma unroll
  for (int i=0;i<4;i++){
    int id = t + 256*i; int row = id>>4, c4 = (id&15)<<2;
    float4 v = *(const float4*)(W + (k0+row)*512 + n0 + c4);
    s16x4 o; o[0]=(short)f2bf(v.x); o[1]=(short)f2bf(v.y); o[2]=(short)f2bf(v.z); o[3]=(short)f2bf(v.w);
    *(s16x4*)(L + row*68 + c4) = o;
  }
  __syncthreads();
#pragma unroll
  for (int i=0;i<2;i++){
    int id = t + 256*i; int nl = id>>3, slot = id&7;
    s16x8 v;
#pragma unroll
    for (int j=0;j<8;j++) v[j] = (short)L[(slot*8+j)*68 + nl];
    *(s16x8*)(dst + (n0+nl)*512 + k0 + slot*8) = v;
  }
}

// ---------------- projections: X[8192x512]f32 @ W -> bf16 tensors ----------------
// job 0=Q (dual out Qu,Qv), 1=K, 2=P, 3=V(transposed out)
__global__ __launch_bounds__(256,2) void k_proj(
  const float* __restrict__ Xq, const float* __restrict__ Xk,
  const float* __restrict__ Xv, const float* __restrict__ Xp,
  const u16* __restrict__ WT,
  const float* __restrict__ bq, const float* __restrict__ bk, const float* __restrict__ bv,
  const float* __restrict__ ub, const float* __restrict__ vb,
  u16* __restrict__ Qu, u16* __restrict__ Qv, u16* __restrict__ Kb,
  u16* __restrict__ Pb, u16* __restrict__ Vt)
{
  const int job = blockIdx.z;
  const float* X = (job==0)?Xq:(job==1)?Xk:(job==2)?Xp:Xv;
  const int wsel = (job==0)?0:(job==1)?1:(job==2)?3:2;
  const u16* W = WT + wsel*262144;
  const int m0 = blockIdx.y*128, n0 = blockIdx.x*128;
  __shared__ u16 As[128*64];
  __shared__ u16 Bs[128*64];
  const int t = threadIdx.x, lane = t&63, w = t>>6;
  const int wm = w&1, wn = w>>1;
  f32x4 acc[4][4];
#pragma unroll
  for (int i=0;i<4;i++)
#pragma unroll
    for (int j=0;j<4;j++) acc[i][j] = (f32x4){0.f,0.f,0.f,0.f};

  for (int kt=0; kt<8; ++kt){
    const int k0 = kt*64;
    __syncthreads();
#pragma unroll
    for (int i=0;i<8;i++){
      int id = t + 256*i; int row = id>>4; int c4 = (id&15)<<2;
      float4 v = *(const float4*)(X + (m0+row)*512 + k0 + c4);
      s16x4 o; o[0]=(short)f2bf(v.x); o[1]=(short)f2bf(v.y); o[2]=(short)f2bf(v.z); o[3]=(short)f2bf(v.w);
      *(s16x4*)(As + row*64 + ((((c4>>3)^(row&7))<<3) + (c4&4))) = o;
    }
#pragma unroll
    for (int i=0;i<4;i++){
      int id = t + 256*i; int row = id>>3, slot = id&7;
      s16x8 v = *(const s16x8*)(W + (n0+row)*512 + k0 + slot*8);
      *(s16x8*)(Bs + row*64 + ((slot^(row&7))<<3)) = v;
    }
    __syncthreads();
#pragma unroll
    for (int kk=0;kk<2;kk++){
      const int slotk = kk*4 + (lane>>4);
      s16x8 xf[4], wf[4];
#pragma unroll
      for (int j=0;j<4;j++){ int r = wm*64 + j*16 + (lane&15); xf[j] = frag64(As, r, slotk); }
#pragma unroll
      for (int i=0;i<4;i++){ int r = wn*64 + i*16 + (lane&15); wf[i] = frag64(Bs, r, slotk); }
      if (job != 3){
#pragma unroll
        for (int i=0;i<4;i++)
#pragma unroll
          for (int j=0;j<4;j++) acc[i][j] = MF(wf[i], xf[j], acc[i][j]);   // D[n][m]
      } else {
#pragma unroll
        for (int i=0;i<4;i++)
#pragma unroll
          for (int j=0;j<4;j++) acc[i][j] = MF(xf[i], wf[j], acc[i][j]);   // D[m][n]
      }
    }
  }

  const int b = m0>>10;
  if (job != 3){
#pragma unroll
    for (int i=0;i<4;i++){
      const int n = n0 + wn*64 + i*16 + ((lane>>4)<<2);
      const int hh = n>>6, d = n&63;
      f32x4 b1 = {0.f,0.f,0.f,0.f}, b2 = {0.f,0.f,0.f,0.f};
      if (job==0){
        f32x4 q4 = *(const f32x4*)(bq+n); f32x4 u4 = *(const f32x4*)(ub+n); f32x4 v4 = *(const f32x4*)(vb+n);
        b1 = q4 + u4; b2 = q4 + v4;
      } else if (job==1){
        b1 = *(const f32x4*)(bk+n);
      }
#pragma unroll
      for (int j=0;j<4;j++){
        const int m = m0 + wm*64 + j*16 + (lane&15);
        const int s = m&1023;
        const int off = ((b*8+hh)*1024 + s)*64 + d;
        f32x4 a = acc[i][j];
        s16x4 o1;
#pragma unroll
        for (int r=0;r<4;r++) o1[r] = (short)f2bf(a[r]+b1[r]);
        if (job==0){
          *(s16x4*)(Qu+off) = o1;
          s16x4 o2;
#pragma unroll
          for (int r=0;r<4;r++) o2[r] = (short)f2bf(a[r]+b2[r]);
          *(s16x4*)(Qv+off) = o2;
        } else if (job==1) *(s16x4*)(Kb+off) = o1;
        else               *(s16x4*)(Pb+off) = o1;
      }
    }
  } else {
#pragma unroll
    for (int j=0;j<4;j++){
      const int n = n0 + wn*64 + j*16 + (lane&15);
      const int hh = n>>6, d = n&63;
      const float bvn = bv[n];
#pragma unroll
      for (int i=0;i<4;i++){
        const int m = m0 + wm*64 + i*16 + ((lane>>4)<<2);
        const int s = m&1023;
        f32x4 a = acc[i][j];
        s16x4 o;
#pragma unroll
        for (int r=0;r<4;r++) o[r] = (short)f2bf(a[r]+bvn);
        *(s16x4*)(Vt + ((b*8+hh)*64 + d)*1024 + s) = o;
      }
    }
  }
}

// ---------------- fused rel-shift attention (deterministic: write-once + gather) ----------------
#define SC_SLOT(q, slot) ((((slot)) & ~7) | ((((slot))&7) ^ ((q)&7)))
#define PS_STRIDE 1032

__global__ __launch_bounds__(512,2) void k_attn(
  const u16* __restrict__ Qu, const u16* __restrict__ Qv,
  const u16* __restrict__ Kb, const u16* __restrict__ Pb,
  const u16* __restrict__ Vt, u16* __restrict__ Ctx)
{
  const int qb = blockIdx.x, h = blockIdx.y, b = blockIdx.z;
  const int q0 = qb*32;
  const int bh = b*8 + h;
  const u16* Qu_ = Qu + bh*65536;
  const u16* Qv_ = Qv + bh*65536;
  const u16* Kb_ = Kb + bh*65536;
  const u16* Pb_ = Pb + bh*65536;
  const u16* Vt_ = Vt + bh*65536;
  u16* Ctx_ = Ctx + bh*65536;
  __shared__ u16 sc[32*1024];          // content+pos scores, then probs (bf16, swizzled rows)
  __shared__ u16 ps[33*PS_STRIDE];     // raw PS strip rows q0..q0+32 (linear)
  __shared__ u16 Ts[64*64];
  __shared__ u16 Qs[48*64];
  __shared__ float stats[32];
  const int t = threadIdx.x, lane = t&63, w = t>>6;

  // ---- stage Qv rows q0..q0+47 (clamped) into Qs
  if (t < 384){
    int row = t>>3, slot = t&7;
    int s = q0 + row; if (s > 1023) s = 1023;
    s16x8 v = *(const s16x8*)(Qv_ + s*64 + slot*8);
    *(s16x8*)(Qs + row*64 + ((slot^(row&7))<<3)) = v;
  }

  // ---- phase 1: PS[q][j] = Qv[q] . P[j], raw (unshifted), rows 0..32 rel
  for (int u=0; u<16; ++u){
    __syncthreads();
    stage64_512(Ts, Pb_ + u*4096, 64, t);
    __syncthreads();
#pragma unroll
    for (int x=0;x<2;x++){
      const int unit = w + 8*x;                 // 0..15, valid <12
      if (unit < 12){
        const int band = unit>>2, jt = unit&3;
        f32x4 psacc = {0.f,0.f,0.f,0.f};
#pragma unroll
        for (int kk=0;kk<2;kk++){
          const int slotk = kk*4 + (lane>>4);
          s16x8 qf = frag64(Qs, band*16 + (lane&15), slotk);
          s16x8 pf = frag64(Ts, jt*16 + (lane&15), slotk);
          psacc = MF(qf, pf, psacc);            // D[q_local][j]
        }
        const int jg = u*64 + jt*16 + (lane&15);
        const int pr0 = band*16 + ((lane>>4)<<2);
#pragma unroll
        for (int r=0;r<4;r++){
          const int prow = pr0 + r;
          if (prow <= 32) ps[prow*PS_STRIDE + jg] = f2bf(psacc[r]);
        }
      }
    }
  }

  // ---- restage Qs with Qu rows q0..q0+31
  __syncthreads();
  if (t < 256){
    int row = t>>3, slot = t&7;
    s16x8 v = *(const s16x8*)(Qu_ + (q0+row)*64 + slot*8);
    *(s16x8*)(Qs + row*64 + ((slot^(row&7))<<3)) = v;
  }

  // ---- phase 2: content Qu.K^T, epilogue gathers rel-shifted pos from ps, writes sc once
  const int qband = w&1, ktile = w>>1;          // 2 x 4 = 8 waves cover 32q x 64k per tile
  for (int kt=0; kt<16; ++kt){
    __syncthreads();
    stage64_512(Ts, Kb_ + kt*4096, 64, t);
    __syncthreads();
    f32x4 a = {0.f,0.f,0.f,0.f};
#pragma unroll
    for (int kk=0;kk<2;kk++){
      const int slotk = kk*4 + (lane>>4);
      s16x8 kf = frag64(Ts, ktile*16 + (lane&15), slotk);
      s16x8 qf = frag64(Qs, qband*16 + (lane&15), slotk);
      a = MF(kf, qf, a);                        // D[k_local][q]
    }
    const int qi = qband*16 + (lane&15);
    const int q  = q0 + qi;
    const int kb2 = kt*64 + ktile*16 + ((lane>>4)<<2);
    s16x4 o;
#pragma unroll
    for (int r=0;r<4;r++){
      const int k = kb2 + r;
      float posv;
      if (k <= q)        posv = bf2f(ps[qi*PS_STRIDE + 1023 - q + k]);
      else if (k == q+1) posv = 0.f;
      else               posv = bf2f(ps[(qi+1)*PS_STRIDE + (k - q - 2)]);
      o[r] = (short)f2bf(a[r] + posv);
    }
    const int slot = kb2>>3;
    *(s16x4*)(sc + qi*1024 + SC_SLOT(qi,slot)*8 + (kb2&4)) = o;
  }

  // ---- softmax over k (scale 1/sqrt(512) folded into exp); 16 threads/row
  __syncthreads();
  {
    const int row = t>>4, c = t&15;
    float mx = -1e30f;
#pragma unroll
    for (int i=0;i<8;i++){
      const int slot = c + 16*i;
      s16x8 v = *(const s16x8*)(sc + row*1024 + SC_SLOT(row,slot)*8);
#pragma unroll
      for (int j2=0;j2<8;j2++) mx = fmaxf(mx, bf2f((u16)v[j2]));
    }
    mx = fmaxf(mx, __shfl_xor(mx,1));
    mx = fmaxf(mx, __shfl_xor(mx,2));
    mx = fmaxf(mx, __shfl_xor(mx,4));
    mx = fmaxf(mx, __shfl_xor(mx,8));
    float sum = 0.f;
    const float SCALE = 0.044194173824159216f;
#pragma unroll
    for (int i=0;i<8;i++){
      const int slot = c + 16*i;
      u16* p = sc + row*1024 + SC_SLOT(row,slot)*8;
      s16x8 v = *(const s16x8*)p;
      s16x8 o;
#pragma unroll
      for (int j2=0;j2<8;j2++){
        float e = __expf((bf2f((u16)v[j2]) - mx)*SCALE);
        sum += e; o[j2] = (short)f2bf(e);
      }
      *(s16x8*)p = o;
    }
    sum += __shfl_xor(sum,1); sum += __shfl_xor(sum,2);
    sum += __shfl_xor(sum,4); sum += __shfl_xor(sum,8);
    if (c==0) stats[row] = 1.0f/sum;
  }

  // ---- PV: D[d][q] = sum_k V^T[d][k] P^T[k][q]; one 16x16 tile per wave
  f32x4 accC = {0.f,0.f,0.f,0.f};
  const int dtile = w>>1;                       // 0..3
  for (int kt=0; kt<16; ++kt){
    __syncthreads();
    stage64_512(Ts, Vt_ + kt*64, 1024, t);
    __syncthreads();
#pragma unroll
    for (int kk=0;kk<2;kk++){
      const int slotk = kk*4 + (lane>>4);
      s16x8 vf = frag64(Ts, dtile*16 + (lane&15), slotk);
      const int qi = qband*16 + (lane&15);
      const int slot = kt*8 + kk*4 + (lane>>4);
      s16x8 pfr = *(const s16x8*)(sc + qi*1024 + SC_SLOT(qi,slot)*8);
      accC = MF(vf, pfr, accC);
    }
  }
  {
    const int qi = qband*16 + (lane&15);
    const float inv = stats[qi];
    const int d0 = dtile*16 + ((lane>>4)<<2);
    s16x4 o;
#pragma unroll
    for (int r=0;r<4;r++) o[r] = (short)f2bf(accC[r]*inv);
    *(s16x4*)(Ctx_ + (q0+qi)*64 + d0) = o;
  }
}

// ---------------- output projection: Out = Ctx @ Wo + bo (f32 out) ----------------
__global__ __launch_bounds__(256,2) void k_out(
  const u16* __restrict__ Ctx, const u16* __restrict__ WT,
  const float* __restrict__ bo, float* __restrict__ Out)
{
  const u16* W = WT + 4*262144;
  const int m0 = blockIdx.y*128, n0 = blockIdx.x*128;
  const int b = m0>>10, s0 = m0&1023;
  __shared__ u16 As[128*64];
  __shared__ u16 Bs[128*64];
  const int t = threadIdx.x, lane = t&63, w = t>>6;
  const int wm = w&1, wn = w>>1;
  f32x4 acc[4][4];
#pragma unroll
  for (int i=0;i<4;i++)
#pragma unroll
    for (int j=0;j<4;j++) acc[i][j] = (f32x4){0.f,0.f,0.f,0.f};

  for (int kt=0; kt<8; ++kt){
    const int k0 = kt*64, hh = kt;
    __syncthreads();
#pragma unroll
    for (int i=0;i<4;i++){
      int id = t + 256*i; int row = id>>3, slot = id&7;
      s16x8 v = *(const s16x8*)(Ctx + ((b*8+hh)*1024 + s0 + row)*64 + slot*8);
      *(s16x8*)(As + row*64 + ((slot^(row&7))<<3)) = v;
    }
#pragma unroll
    for (int i=0;i<4;i++){
      int id = t + 256*i; int row = id>>3, slot = id&7;
      s16x8 v = *(const s16x8*)(W + (n0+row)*512 + k0 + slot*8);
      *(s16x8*)(Bs + row*64 + ((slot^(row&7))<<3)) = v;
    }
    __syncthreads();
#pragma unroll
    for (int kk=0;kk<2;kk++){
      const int slotk = kk*4 + (lane>>4);
      s16x8 xf[4], wf[4];
#pragma unroll
      for (int j=0;j<4;j++){ int r = wm*64 + j*16 + (lane&15); xf[j] = frag64(As, r, slotk); }
#pragma unroll
      for (int i=0;i<4;i++){ int r = wn*64 + i*16 + (lane&15); wf[i] = frag64(Bs, r, slotk); }
#pragma unroll
      for (int i=0;i<4;i++)
#pragma unroll
        for (int j=0;j<4;j++) acc[i][j] = MF(wf[i], xf[j], acc[i][j]);  // D[n][m]
    }
  }
#pragma unroll
  for (int i=0;i<4;i++){
    const int n = n0 + wn*64 + i*16 + ((lane>>4)<<2);
    f32x4 bo4 = *(const f32x4*)(bo + n);
#pragma unroll
    for (int j=0;j<4;j++){
      const int m = m0 + wm*64 + j*16 + (lane&15);
      f32x4 o = acc[i][j] + bo4;
      *(f32x4*)(Out + m*512 + n) = o;
    }
  }
}

extern "C" void kernel_launch(void* const* d_in, const int* in_sizes, int n_in,
                              void* d_out, int out_size, void* d_ws, size_t ws_size,
                              hipStream_t stream)
{
  const float* query = (const float*)d_in[0];
  const float* key   = (const float*)d_in[1];
  const float* value = (const float*)d_in[2];
  const float* pos   = (const float*)d_in[3];
  const float* Wq = (const float*)d_in[4];
  const float* bq = (const float*)d_in[5];
  const float* Wk = (const float*)d_in[6];
  const float* bk = (const float*)d_in[7];
  const float* Wv = (const float*)d_in[8];
  const float* bv = (const float*)d_in[9];
  const float* Wp = (const float*)d_in[10];
  const float* Wo = (const float*)d_in[11];
  const float* bo = (const float*)d_in[12];
  const float* ub = (const float*)d_in[13];
  const float* vb = (const float*)d_in[14];
  float* Out = (float*)d_out;

  u16* ws  = (u16*)d_ws;
  u16* WT  = ws;                       // 5 * 262144
  u16* Qu  = ws + 1310720;             // each tensor: 8*8*1024*64 = 4194304
  u16* Qv  = Qu + 4194304;
  u16* Kb  = Qv + 4194304;
  u16* Pb  = Kb + 4194304;
  u16* Vt  = Pb + 4194304;
  u16* Ctx = Vt + 4194304;

  k_prep<<<dim3(320),      dim3(256), 0, stream>>>(Wq,Wk,Wv,Wp,Wo,WT);
  k_proj<<<dim3(4,64,4),   dim3(256), 0, stream>>>(query,key,value,pos,WT,bq,bk,bv,ub,vb,Qu,Qv,Kb,Pb,Vt);
  k_attn<<<dim3(32,8,8),   dim3(512), 0, stream>>>(Qu,Qv,Kb,Pb,Vt,Ctx);
  k_out<<<dim3(4,64),      dim3(256), 0, stream>>>(Ctx,WT,bo,Out);
}

// Round 3
// 182.418 us; speedup vs baseline: 1.8581x; 1.8581x over previous
//
#include <hip/hip_runtime.h>

typedef unsigned short u16;
typedef unsigned int u32;
typedef __attribute__((ext_vector_type(4))) float f32x4;
typedef __attribute__((ext_vector_type(8))) short s16x8;
typedef __attribute__((ext_vector_type(4))) short s16x4;

#define DEV static __device__ __forceinline__

DEV u16 f2bf(float f){ union{float f;u32 u;}x; x.f=f; u32 u = x.u + 0x7fffu + ((x.u>>16)&1u); return (u16)(u>>16); }
DEV float bf2f(u16 v){ union{u32 u;float f;}x; x.u = ((u32)v)<<16; return x.f; }

DEV f32x4 MF(s16x8 a, s16x8 b, f32x4 c){ return __builtin_amdgcn_mfma_f32_16x16x32_bf16(a,b,c,0,0,0); }

// read a 16B MFMA fragment from a swizzled [rows][64] bf16 LDS tile
DEV s16x8 frag64(const u16* lds, int row, int slot){
  return *(const s16x8*)(lds + row*64 + ((slot ^ (row&7))<<3));
}

// ---------------- prep: W[k][n] f32 -> WT[n][k] bf16, 5 matrices ----------------
__global__ __launch_bounds__(256) void k_prep(
  const float* __restrict__ Wq, const float* __restrict__ Wk, const float* __restrict__ Wv,
  const float* __restrict__ Wp, const float* __restrict__ Wo, u16* __restrict__ WT)
{
  const int bx = blockIdx.x; const int mat = bx>>6, tile = bx&63;
  const float* W = (mat==0)?Wq:(mat==1)?Wk:(mat==2)?Wv:(mat==3)?Wp:Wo;
  u16* dst = WT + mat*262144;
  const int k0 = (tile>>3)<<6, n0 = (tile&7)<<6;
  __shared__ u16 L[64*68];
  const int t = threadIdx.x;
#pragma unroll
  for (int i=0;i<4;i++){
    int id = t + 256*i; int row = id>>4, c4 = (id&15)<<2;
    float4 v = *(const float4*)(W + (k0+row)*512 + n0 + c4);
    s16x4 o; o[0]=(short)f2bf(v.x); o[1]=(short)f2bf(v.y); o[2]=(short)f2bf(v.z); o[3]=(short)f2bf(v.w);
    *(s16x4*)(L + row*68 + c4) = o;
  }
  __syncthreads();
#pragma unroll
  for (int i=0;i<2;i++){
    int id = t + 256*i; int nl = id>>3, slot = id&7;
    s16x8 v;
#pragma unroll
    for (int j=0;j<8;j++) v[j] = (short)L[(slot*8+j)*68 + nl];
    *(s16x8*)(dst + (n0+nl)*512 + k0 + slot*8) = v;
  }
}

// ---------------- projections: X[8192x512]f32 @ W -> bf16 tensors ----------------
// job 0=Q (dual out Qu,Qv), 1=K, 2=P, 3=V(transposed out)
__global__ __launch_bounds__(256,2) void k_proj(
  const float* __restrict__ Xq, const float* __restrict__ Xk,
  const float* __restrict__ Xv, const float* __restrict__ Xp,
  const u16* __restrict__ WT,
  const float* __restrict__ bq, const float* __restrict__ bk, const float* __restrict__ bv,
  const float* __restrict__ ub, const float* __restrict__ vb,
  u16* __restrict__ Qu, u16* __restrict__ Qv, u16* __restrict__ Kb,
  u16* __restrict__ Pb, u16* __restrict__ Vt)
{
  const int job = blockIdx.z;
  const float* X = (job==0)?Xq:(job==1)?Xk:(job==2)?Xp:Xv;
  const int wsel = (job==0)?0:(job==1)?1:(job==2)?3:2;
  const u16* W = WT + wsel*262144;
  const int m0 = blockIdx.y*128, n0 = blockIdx.x*128;
  __shared__ u16 As[128*64];
  __shared__ u16 Bs[128*64];
  const int t = threadIdx.x, lane = t&63, w = t>>6;
  const int wm = w&1, wn = w>>1;
  f32x4 acc[4][4];
#pragma unroll
  for (int i=0;i<4;i++)
#pragma unroll
    for (int j=0;j<4;j++) acc[i][j] = (f32x4){0.f,0.f,0.f,0.f};

  for (int kt=0; kt<8; ++kt){
    const int k0 = kt*64;
    __syncthreads();
#pragma unroll
    for (int i=0;i<8;i++){
      int id = t + 256*i; int row = id>>4; int c4 = (id&15)<<2;
      float4 v = *(const float4*)(X + (m0+row)*512 + k0 + c4);
      s16x4 o; o[0]=(short)f2bf(v.x); o[1]=(short)f2bf(v.y); o[2]=(short)f2bf(v.z); o[3]=(short)f2bf(v.w);
      *(s16x4*)(As + row*64 + ((((c4>>3)^(row&7))<<3) + (c4&4))) = o;
    }
#pragma unroll
    for (int i=0;i<4;i++){
      int id = t + 256*i; int row = id>>3, slot = id&7;
      s16x8 v = *(const s16x8*)(W + (n0+row)*512 + k0 + slot*8);
      *(s16x8*)(Bs + row*64 + ((slot^(row&7))<<3)) = v;
    }
    __syncthreads();
#pragma unroll
    for (int kk=0;kk<2;kk++){
      const int slotk = kk*4 + (lane>>4);
      s16x8 xf[4], wf[4];
#pragma unroll
      for (int j=0;j<4;j++){ int r = wm*64 + j*16 + (lane&15); xf[j] = frag64(As, r, slotk); }
#pragma unroll
      for (int i=0;i<4;i++){ int r = wn*64 + i*16 + (lane&15); wf[i] = frag64(Bs, r, slotk); }
      if (job != 3){
#pragma unroll
        for (int i=0;i<4;i++)
#pragma unroll
          for (int j=0;j<4;j++) acc[i][j] = MF(wf[i], xf[j], acc[i][j]);   // D[n][m]
      } else {
#pragma unroll
        for (int i=0;i<4;i++)
#pragma unroll
          for (int j=0;j<4;j++) acc[i][j] = MF(xf[i], wf[j], acc[i][j]);   // D[m][n]
      }
    }
  }

  const int b = m0>>10;
  if (job != 3){
#pragma unroll
    for (int i=0;i<4;i++){
      const int n = n0 + wn*64 + i*16 + ((lane>>4)<<2);
      const int hh = n>>6, d = n&63;
      f32x4 b1 = {0.f,0.f,0.f,0.f}, b2 = {0.f,0.f,0.f,0.f};
      if (job==0){
        f32x4 q4 = *(const f32x4*)(bq+n); f32x4 u4 = *(const f32x4*)(ub+n); f32x4 v4 = *(const f32x4*)(vb+n);
        b1 = q4 + u4; b2 = q4 + v4;
      } else if (job==1){
        b1 = *(const f32x4*)(bk+n);
      }
#pragma unroll
      for (int j=0;j<4;j++){
        const int m = m0 + wm*64 + j*16 + (lane&15);
        const int s = m&1023;
        const int off = ((b*8+hh)*1024 + s)*64 + d;
        f32x4 a = acc[i][j];
        s16x4 o1;
#pragma unroll
        for (int r=0;r<4;r++) o1[r] = (short)f2bf(a[r]+b1[r]);
        if (job==0){
          *(s16x4*)(Qu+off) = o1;
          s16x4 o2;
#pragma unroll
          for (int r=0;r<4;r++) o2[r] = (short)f2bf(a[r]+b2[r]);
          *(s16x4*)(Qv+off) = o2;
        } else if (job==1) *(s16x4*)(Kb+off) = o1;
        else               *(s16x4*)(Pb+off) = o1;
      }
    }
  } else {
#pragma unroll
    for (int j=0;j<4;j++){
      const int n = n0 + wn*64 + j*16 + (lane&15);
      const int hh = n>>6, d = n&63;
      const float bvn = bv[n];
#pragma unroll
      for (int i=0;i<4;i++){
        const int m = m0 + wm*64 + i*16 + ((lane>>4)<<2);
        const int s = m&1023;
        f32x4 a = acc[i][j];
        s16x4 o;
#pragma unroll
        for (int r=0;r<4;r++) o[r] = (short)f2bf(a[r]+bvn);
        *(s16x4*)(Vt + ((b*8+hh)*64 + d)*1024 + s) = o;
      }
    }
  }
}

// ---------------- fused rel-shift attention ----------------
// Deterministic scheme:
//   phase 1: PS = Qv.P^T scatter-WRITTEN (write-once, disjoint targets) into sc
//            at rel-shifted positions; k=q+1 column zero-filled.
//   phase 2: content Qu.K^T added via owner-thread RMW (each cell one thread).
//   softmax in place; PV from prob strip.
// LDS = 80000 B -> 2 blocks/CU; reg-staged prefetch hides HBM latency.
#define SC_SLOT(q, slot) ((((slot)) & ~7) | ((((slot))&7) ^ ((q)&7)))

__global__ __launch_bounds__(512,2) void k_attn(
  const u16* __restrict__ Qu, const u16* __restrict__ Qv,
  const u16* __restrict__ Kb, const u16* __restrict__ Pb,
  const u16* __restrict__ Vt, u16* __restrict__ Ctx)
{
  const int qb = blockIdx.x, h = blockIdx.y, b = blockIdx.z;
  const int q0 = qb*32;
  const int bh = b*8 + h;
  const u16* Qu_ = Qu + bh*65536;
  const u16* Qv_ = Qv + bh*65536;
  const u16* Kb_ = Kb + bh*65536;
  const u16* Pb_ = Pb + bh*65536;
  const u16* Vt_ = Vt + bh*65536;
  u16* Ctx_ = Ctx + bh*65536;
  __shared__ u16 sc[32*1024];          // pos scores -> +content -> probs (bf16, swizzled rows)
  __shared__ u16 Ts[64*64];
  __shared__ u16 Qs[48*64];
  __shared__ float stats[32];
  const int t = threadIdx.x, lane = t&63, w = t>>6;
  const int srow = t>>3, sslot = t&7;  // staging coords (512 thr, 1 chunk each)

  // ---- stage Qv rows q0..q0+47 (clamped) into Qs
  if (t < 384){
    int row = t>>3, slot = t&7;
    int s = q0 + row; if (s > 1023) s = 1023;
    s16x8 v = *(const s16x8*)(Qv_ + s*64 + slot*8);
    *(s16x8*)(Qs + row*64 + ((slot^(row&7))<<3)) = v;
  }
  // ---- zero-fill the k=q+1 cells (disjoint from all scatter targets)
  if (t < 32){
    const int k = q0 + t + 1;
    if (k <= 1023) sc[t*1024 + SC_SLOT(t, k>>3)*8 + (k&7)] = 0;
  }

  // ---- phase 1: PS[prow][jg] = Qv[q0+prow] . P[jg], scattered rel-shifted into sc
  {
    s16x8 vT = *(const s16x8*)(Pb_ + srow*64 + sslot*8);
    for (int u=0; u<16; ++u){
      __syncthreads();
      *(s16x8*)(Ts + srow*64 + ((sslot^(srow&7))<<3)) = vT;
      if (u<15) vT = *(const s16x8*)(Pb_ + (u+1)*4096 + srow*64 + sslot*8);
      __syncthreads();
#pragma unroll
      for (int x=0;x<2;x++){
        const int unit = w + 8*x;                 // 0..15, valid <12
        if (unit < 12){
          const int band = unit>>2, jt = unit&3;
          f32x4 psacc = {0.f,0.f,0.f,0.f};
#pragma unroll
          for (int kk=0;kk<2;kk++){
            const int slotk = kk*4 + (lane>>4);
            s16x8 qf = frag64(Qs, band*16 + (lane&15), slotk);
            s16x8 pf = frag64(Ts, jt*16 + (lane&15), slotk);
            psacc = MF(qf, pf, psacc);            // D[q_local][j]
          }
          const int jg = u*64 + jt*16 + (lane&15);
          const int pr0 = band*16 + ((lane>>4)<<2);
#pragma unroll
          for (int r=0;r<4;r++){
            const int prow = pr0 + r;
            const int q = q0 + prow;
            const u16 bv16 = f2bf(psacc[r]);
            // case A: sc[prow][k], k = jg-1023+q, valid iff jg >= 1023-q, prow<32
            if (prow < 32 && jg >= 1023 - q){
              const int k = jg - 1023 + q;
              sc[prow*1024 + SC_SLOT(prow, k>>3)*8 + (k&7)] = bv16;
            }
            // case B: sc[prow-1][k2], k2 = jg+q+1, valid iff jg <= 1022-q, 1<=prow<=32
            if (prow >= 1 && prow <= 32 && jg <= 1022 - q){
              const int k2 = jg + q + 1;
              const int row2 = prow - 1;
              sc[row2*1024 + SC_SLOT(row2, k2>>3)*8 + (k2&7)] = bv16;
            }
          }
        }
      }
    }
  }

  // ---- restage Qs with Qu rows q0..q0+31
  __syncthreads();
  if (t < 256){
    int row = t>>3, slot = t&7;
    s16x8 v = *(const s16x8*)(Qu_ + (q0+row)*64 + slot*8);
    *(s16x8*)(Qs + row*64 + ((slot^(row&7))<<3)) = v;
  }

  // ---- phase 2: content Qu.K^T, owner-thread RMW add into sc
  const int qband = w&1, ktile = w>>1;          // 2 x 4 = 8 waves cover 32q x 64k per tile
  {
    s16x8 vK = *(const s16x8*)(Kb_ + srow*64 + sslot*8);
    for (int kt=0; kt<16; ++kt){
      __syncthreads();
      *(s16x8*)(Ts + srow*64 + ((sslot^(srow&7))<<3)) = vK;
      if (kt<15) vK = *(const s16x8*)(Kb_ + (kt+1)*4096 + srow*64 + sslot*8);
      __syncthreads();
      f32x4 a = {0.f,0.f,0.f,0.f};
#pragma unroll
      for (int kk=0;kk<2;kk++){
        const int slotk = kk*4 + (lane>>4);
        s16x8 kf = frag64(Ts, ktile*16 + (lane&15), slotk);
        s16x8 qf = frag64(Qs, qband*16 + (lane&15), slotk);
        a = MF(kf, qf, a);                        // D[k_local][q]
      }
      const int qi = qband*16 + (lane&15);
      const int kb2 = kt*64 + ktile*16 + ((lane>>4)<<2);
      u16* p = sc + qi*1024 + SC_SLOT(qi, kb2>>3)*8 + (kb2&4);
      s16x4 cur = *(s16x4*)p;
      s16x4 o;
#pragma unroll
      for (int r=0;r<4;r++) o[r] = (short)f2bf(bf2f((u16)cur[r]) + a[r]);
      *(s16x4*)p = o;
    }
  }

  // ---- softmax over k (scale 1/sqrt(512) folded into exp); 16 threads/row
  __syncthreads();
  {
    const int row = t>>4, c = t&15;
    float mx = -1e30f;
#pragma unroll
    for (int i=0;i<8;i++){
      const int slot = c + 16*i;
      s16x8 v = *(const s16x8*)(sc + row*1024 + SC_SLOT(row,slot)*8);
#pragma unroll
      for (int j2=0;j2<8;j2++) mx = fmaxf(mx, bf2f((u16)v[j2]));
    }
    mx = fmaxf(mx, __shfl_xor(mx,1));
    mx = fmaxf(mx, __shfl_xor(mx,2));
    mx = fmaxf(mx, __shfl_xor(mx,4));
    mx = fmaxf(mx, __shfl_xor(mx,8));
    float sum = 0.f;
    const float SCALE = 0.044194173824159216f;
#pragma unroll
    for (int i=0;i<8;i++){
      const int slot = c + 16*i;
      u16* p = sc + row*1024 + SC_SLOT(row,slot)*8;
      s16x8 v = *(const s16x8*)p;
      s16x8 o;
#pragma unroll
      for (int j2=0;j2<8;j2++){
        float e = __expf((bf2f((u16)v[j2]) - mx)*SCALE);
        sum += e; o[j2] = (short)f2bf(e);
      }
      *(s16x8*)p = o;
    }
    sum += __shfl_xor(sum,1); sum += __shfl_xor(sum,2);
    sum += __shfl_xor(sum,4); sum += __shfl_xor(sum,8);
    if (c==0) stats[row] = 1.0f/sum;
  }

  // ---- PV: D[d][q] = sum_k V^T[d][k] P^T[k][q]; one 16x16 tile per wave
  f32x4 accC = {0.f,0.f,0.f,0.f};
  const int dtile = w>>1;                       // 0..3
  {
    s16x8 vV = *(const s16x8*)(Vt_ + srow*1024 + sslot*8);
    for (int kt=0; kt<16; ++kt){
      __syncthreads();
      *(s16x8*)(Ts + srow*64 + ((sslot^(srow&7))<<3)) = vV;
      if (kt<15) vV = *(const s16x8*)(Vt_ + srow*1024 + (kt+1)*64 + sslot*8);
      __syncthreads();
#pragma unroll
      for (int kk=0;kk<2;kk++){
        const int slotk = kk*4 + (lane>>4);
        s16x8 vf = frag64(Ts, dtile*16 + (lane&15), slotk);
        const int qi = qband*16 + (lane&15);
        const int slot = kt*8 + kk*4 + (lane>>4);
        s16x8 pfr = *(const s16x8*)(sc + qi*1024 + SC_SLOT(qi,slot)*8);
        accC = MF(vf, pfr, accC);
      }
    }
  }
  {
    const int qi = qband*16 + (lane&15);
    const float inv = stats[qi];
    const int d0 = dtile*16 + ((lane>>4)<<2);
    s16x4 o;
#pragma unroll
    for (int r=0;r<4;r++) o[r] = (short)f2bf(accC[r]*inv);
    *(s16x4*)(Ctx_ + (q0+qi)*64 + d0) = o;
  }
}

// ---------------- output projection: Out = Ctx @ Wo + bo (f32 out) ----------------
__global__ __launch_bounds__(256,2) void k_out(
  const u16* __restrict__ Ctx, const u16* __restrict__ WT,
  const float* __restrict__ bo, float* __restrict__ Out)
{
  const u16* W = WT + 4*262144;
  const int m0 = blockIdx.y*128, n0 = blockIdx.x*128;
  const int b = m0>>10, s0 = m0&1023;
  __shared__ u16 As[128*64];
  __shared__ u16 Bs[128*64];
  const int t = threadIdx.x, lane = t&63, w = t>>6;
  const int wm = w&1, wn = w>>1;
  f32x4 acc[4][4];
#pragma unroll
  for (int i=0;i<4;i++)
#pragma unroll
    for (int j=0;j<4;j++) acc[i][j] = (f32x4){0.f,0.f,0.f,0.f};

  for (int kt=0; kt<8; ++kt){
    const int k0 = kt*64, hh = kt;
    __syncthreads();
#pragma unroll
    for (int i=0;i<4;i++){
      int id = t + 256*i; int row = id>>3, slot = id&7;
      s16x8 v = *(const s16x8*)(Ctx + ((b*8+hh)*1024 + s0 + row)*64 + slot*8);
      *(s16x8*)(As + row*64 + ((slot^(row&7))<<3)) = v;
    }
#pragma unroll
    for (int i=0;i<4;i++){
      int id = t + 256*i; int row = id>>3, slot = id&7;
      s16x8 v = *(const s16x8*)(W + (n0+row)*512 + k0 + slot*8);
      *(s16x8*)(Bs + row*64 + ((slot^(row&7))<<3)) = v;
    }
    __syncthreads();
#pragma unroll
    for (int kk=0;kk<2;kk++){
      const int slotk = kk*4 + (lane>>4);
      s16x8 xf[4], wf[4];
#pragma unroll
      for (int j=0;j<4;j++){ int r = wm*64 + j*16 + (lane&15); xf[j] = frag64(As, r, slotk); }
#pragma unroll
      for (int i=0;i<4;i++){ int r = wn*64 + i*16 + (lane&15); wf[i] = frag64(Bs, r, slotk); }
#pragma unroll
      for (int i=0;i<4;i++)
#pragma unroll
        for (int j=0;j<4;j++) acc[i][j] = MF(wf[i], xf[j], acc[i][j]);  // D[n][m]
    }
  }
#pragma unroll
  for (int i=0;i<4;i++){
    const int n = n0 + wn*64 + i*16 + ((lane>>4)<<2);
    f32x4 bo4 = *(const f32x4*)(bo + n);
#pragma unroll
    for (int j=0;j<4;j++){
      const int m = m0 + wm*64 + j*16 + (lane&15);
      f32x4 o = acc[i][j] + bo4;
      *(f32x4*)(Out + m*512 + n) = o;
    }
  }
}

extern "C" void kernel_launch(void* const* d_in, const int* in_sizes, int n_in,
                              void* d_out, int out_size, void* d_ws, size_t ws_size,
                              hipStream_t stream)
{
  const float* query = (const float*)d_in[0];
  const float* key   = (const float*)d_in[1];
  const float* value = (const float*)d_in[2];
  const float* pos   = (const float*)d_in[3];
  const float* Wq = (const float*)d_in[4];
  const float* bq = (const float*)d_in[5];
  const float* Wk = (const float*)d_in[6];
  const float* bk = (const float*)d_in[7];
  const float* Wv = (const float*)d_in[8];
  const float* bv = (const float*)d_in[9];
  const float* Wp = (const float*)d_in[10];
  const float* Wo = (const float*)d_in[11];
  const float* bo = (const float*)d_in[12];
  const float* ub = (const float*)d_in[13];
  const float* vb = (const float*)d_in[14];
  float* Out = (float*)d_out;

  u16* ws  = (u16*)d_ws;
  u16* WT  = ws;                       // 5 * 262144
  u16* Qu  = ws + 1310720;             // each tensor: 8*8*1024*64 = 4194304
  u16* Qv  = Qu + 4194304;
  u16* Kb  = Qv + 4194304;
  u16* Pb  = Kb + 4194304;
  u16* Vt  = Pb + 4194304;
  u16* Ctx = Vt + 4194304;

  k_prep<<<dim3(320),      dim3(256), 0, stream>>>(Wq,Wk,Wv,Wp,Wo,WT);
  k_proj<<<dim3(4,64,4),   dim3(256), 0, stream>>>(query,key,value,pos,WT,bq,bk,bv,ub,vb,Qu,Qv,Kb,Pb,Vt);
  k_attn<<<dim3(32,8,8),   dim3(512), 0, stream>>>(Qu,Qv,Kb,Pb,Vt,Ctx);
  k_out<<<dim3(4,64),      dim3(256), 0, stream>>>(Ctx,WT,bo,Out);
}